// Round 4
// baseline (505.110 us; speedup 1.0000x reference)
//
#include <hip/hip_runtime.h>
#include <math.h>

#define LSZ 128
#define NCH 8
#define NLAY 16

__device__ __forceinline__ float4 f4add(float4 a, float4 b) {
    return make_float4(a.x + b.x, a.y + b.y, a.z + b.z, a.w + b.w);
}
__device__ __forceinline__ float4 f4fma(float s, float4 a, float4 acc) {
    return make_float4(fmaf(s, a.x, acc.x), fmaf(s, a.y, acc.y),
                       fmaf(s, a.z, acc.z), fmaf(s, a.w, acc.w));
}
__device__ __forceinline__ float4 f4scale(float s, float4 a) {
    return make_float4(s * a.x, s * a.y, s * a.z, s * a.w);
}
// CELU(y) = max(y,0) + exp(min(y,0)) - 1 ; exact for y>=0, ~1e-7 abs err for y<0.
__device__ __forceinline__ float celu1(float y) {
    return fmaxf(y, 0.f) + (__expf(fminf(y, 0.f)) - 1.f);
}
// wave-uniform float -> SGPR
__device__ __forceinline__ float uni(float v) {
    return __uint_as_float(__builtin_amdgcn_readfirstlane(__float_as_uint(v)));
}

// One block per (batch, channel) plane. 512 threads: 16 row-strips x 32 col-groups.
// Each thread owns 8 rows x 4 cols. Plane lives in LDS (64 KB), updated in place.
// Own rows carried in registers across layers (cr[4..11]); halo rows re-read.
// __launch_bounds__(512,4): min 4 waves/EU -> VGPR cap 128 = exactly the
// 2-blocks/CU residency tier (LDS caps at 2 blocks anyway). Goal: keep cr[]
// in arch VGPRs, no AGPR shuffling.
__global__ __launch_bounds__(512, 4)
void plane_kernel(const float* __restrict__ nrm,   // (256,128,3)
                  const float* __restrict__ W,     // (16,8,5)
                  float* __restrict__ ws)          // (2048,) per-block sums
{
    __shared__ float x[LSZ * LSZ];     // 65536 B
    __shared__ float nsm[LSZ * 3];     // 1536 B
    __shared__ float wsm[NLAY * 5];    // 320 B
    __shared__ float red[8];

    const int bid = blockIdx.x;
    const int b   = bid >> 3;
    const int c   = bid & 7;
    const int tid = threadIdx.x;

    if (tid < LSZ * 3) nsm[tid] = nrm[b * (LSZ * 3) + tid];
    if (tid < NLAY * 5) {
        int l = tid / 5, d = tid % 5;
        wsm[tid] = W[l * (NCH * 5) + c * 5 + d];
    }
    __syncthreads();

    const int jg = tid & 31;        // col group
    const int is = tid >> 5;        // row strip
    const int j0 = jg * 4;
    const int i0 = is * 8;

    // column cache, rows i0-4 .. i0+11 (wrapped). cr[4..11] = own rows,
    // carried in registers across layers. cr[m] (halo, dead after use at
    // iteration m) doubles as the output stash for row i0+m.
    float4 cr[16];

    // ---- init: g[i][j] = dot3(n[i], n[j]), zero diagonal ----
    {
        float nj0x = nsm[(j0 + 0) * 3 + 0], nj0y = nsm[(j0 + 0) * 3 + 1], nj0z = nsm[(j0 + 0) * 3 + 2];
        float nj1x = nsm[(j0 + 1) * 3 + 0], nj1y = nsm[(j0 + 1) * 3 + 1], nj1z = nsm[(j0 + 1) * 3 + 2];
        float nj2x = nsm[(j0 + 2) * 3 + 0], nj2y = nsm[(j0 + 2) * 3 + 1], nj2z = nsm[(j0 + 2) * 3 + 2];
        float nj3x = nsm[(j0 + 3) * 3 + 0], nj3y = nsm[(j0 + 3) * 3 + 1], nj3z = nsm[(j0 + 3) * 3 + 2];
#pragma unroll
        for (int k = 0; k < 8; ++k) {
            int r = i0 + k;
            float n0 = nsm[r * 3 + 0], n1 = nsm[r * 3 + 1], n2 = nsm[r * 3 + 2];
            float g0 = n0 * nj0x + n1 * nj0y + n2 * nj0z;
            float g1 = n0 * nj1x + n1 * nj1y + n2 * nj1z;
            float g2 = n0 * nj2x + n1 * nj2y + n2 * nj2z;
            float g3 = n0 * nj3x + n1 * nj3y + n2 * nj3z;
            if (r == j0 + 0) g0 = 0.f;
            if (r == j0 + 1) g1 = 0.f;
            if (r == j0 + 2) g2 = 0.f;
            if (r == j0 + 3) g3 = 0.f;
            float4 v = make_float4(g0, g1, g2, g3);
            *(float4*)&x[r * LSZ + j0] = v;
            cr[4 + k] = v;                 // own rows start in registers
        }
    }
    __syncthreads();

    const int jl = (j0 - 4) & (LSZ - 1);
    const int jr = (j0 + 4) & (LSZ - 1);

#pragma unroll 1
    for (int l = 0; l < NLAY; ++l) {
        // weights -> SGPRs (wave-uniform): frees VGPRs, VOP3 scalar operand
        const float w0 = uni(wsm[l * 5 + 0]);
        const float w1 = uni(wsm[l * 5 + 1]);
        const float w2 = uni(wsm[l * 5 + 2]);
        const float w3 = uni(wsm[l * 5 + 3]);
        const float w4 = uni(wsm[l * 5 + 4]);

        // halo rows only (own rows already live in cr[4..11])
#pragma unroll
        for (int k = 0; k < 4; ++k) {
            int rt = (i0 + k - 4) & (LSZ - 1);
            cr[k] = *(const float4*)&x[rt * LSZ + j0];
            int rb = (i0 + 8 + k) & (LSZ - 1);
            cr[12 + k] = *(const float4*)&x[rb * LSZ + j0];
        }

#pragma unroll
        for (int m = 0; m < 8; ++m) {
            const int r = i0 + m;
            const float4 L = *(const float4*)&x[r * LSZ + jl];
            const float4 R = *(const float4*)&x[r * LSZ + jr];
            const float4 C = cr[m + 4];

            // horizontal shifted taps (j-d + j+d), d = 1..4
            float4 h1 = make_float4(L.w + C.y, C.x + C.z, C.y + C.w, C.z + R.x);
            float4 h2 = make_float4(L.z + C.z, L.w + C.w, C.x + R.x, C.y + R.y);
            float4 h3 = make_float4(L.y + C.w, L.z + R.x, L.w + R.y, C.x + R.z);
            float4 h4 = f4add(L, R);

            float4 y = f4scale(w0, C);
            y = f4fma(w1, f4add(h1, f4add(cr[m + 3], cr[m + 5])), y);
            y = f4fma(w2, f4add(h2, f4add(cr[m + 2], cr[m + 6])), y);
            y = f4fma(w3, f4add(h3, f4add(cr[m + 1], cr[m + 7])), y);
            y = f4fma(w4, f4add(h4, f4add(cr[m + 0], cr[m + 8])), y);

            float4 res;
            res.x = C.x + celu1(y.x);
            res.y = C.y + celu1(y.y);
            res.z = C.z + celu1(y.z);
            res.w = C.w + celu1(y.w);
            cr[m] = res;                       // stash (cr[m] dead after this m)
        }
        __syncthreads();
#pragma unroll
        for (int m = 0; m < 8; ++m)
            *(float4*)&x[(i0 + m) * LSZ + j0] = cr[m];
        __syncthreads();

        // carry results into the own-row slots for the next layer
#pragma unroll
        for (int k = 7; k >= 0; --k)
            cr[4 + k] = cr[k];
    }

    // ---- per-block sum of final plane (results live in cr[4..11]) ----
    float local = 0.f;
#pragma unroll
    for (int m = 4; m < 12; ++m)
        local += cr[m].x + cr[m].y + cr[m].z + cr[m].w;

#pragma unroll
    for (int off = 32; off > 0; off >>= 1)
        local += __shfl_down(local, off, 64);

    const int wave = tid >> 6;
    if ((tid & 63) == 0) red[wave] = local;
    __syncthreads();
    if (tid == 0) {
        float s = 0.f;
#pragma unroll
        for (int w = 0; w < 8; ++w) s += red[w];
        ws[bid] = s;
    }
}

__global__ void finish_kernel(const float* __restrict__ ws, float* __restrict__ out) {
    int b = threadIdx.x;
    float s = 0.f;
#pragma unroll
    for (int c = 0; c < NCH; ++c) s += ws[b * NCH + c];
    out[b] = expf(-s / (8.0f * 128.0f * 128.0f));
}

extern "C" void kernel_launch(void* const* d_in, const int* in_sizes, int n_in,
                              void* d_out, int out_size, void* d_ws, size_t ws_size,
                              hipStream_t stream) {
    const float* nrm = (const float*)d_in[0];   // (256,128,3) f32
    const float* W   = (const float*)d_in[1];   // (16,8,5) f32
    float* out = (float*)d_out;                 // (256,) f32
    float* ws  = (float*)d_ws;                  // >= 2048 f32 scratch

    plane_kernel<<<dim3(256 * NCH), dim3(512), 0, stream>>>(nrm, W, ws);
    finish_kernel<<<dim3(1), dim3(256), 0, stream>>>(ws, out);
}